// Round 12
// baseline (378.726 us; speedup 1.0000x reference)
//
#include <hip/hip_runtime.h>
#include <hip/hip_fp16.h>

#define D 64
#define NBMAX 512      // max buckets (nodes/256, N<=131072)
#define BCAP 5120      // per-bucket capacity
#define TILE 64        // nodes per block in tile_layer
#define AST 68         // LDS acc row stride in floats (breaks pow-2 banks, 16B-aligned)
#define ACAP 448       // per-wave LDS adjacency buffer (entries)

typedef __attribute__((ext_vector_type(8))) short short8;
typedef __attribute__((ext_vector_type(4))) float float4v;

static __device__ __forceinline__ unsigned short f2bf(float x) {
    unsigned u = __float_as_uint(x);
    u += 0x7FFFu + ((u >> 16) & 1);   // RNE
    return (unsigned short)(u >> 16);
}

__global__ void zero_ints(int* __restrict__ p, int n) {
    int i = blockIdx.x * blockDim.x + threadIdx.x;
    if (i < n) p[i] = 0;
}

// x (fp32) -> xh (fp16), pre-scaled by dis[row]: s = dis[n]*x[n]
__global__ void prescale_x(const float* __restrict__ x, const float* __restrict__ dis,
                           __half* __restrict__ out, int n2) {
    int i = blockIdx.x * blockDim.x + threadIdx.x;
    if (i < n2) {
        int n = i >> 5;                 // 32 half2 per row
        float d = dis[n];
        float2 v = ((const float2*)x)[i];
        ((__half2*)out)[i] = __floats2half2_rn(v.x * d, v.y * d);
    }
}

// Bin edges into buckets of 256 consecutive dst nodes. Entry packed to 4B:
// (src << 8) | (dst & 255)   (src < 2^24).
__global__ __launch_bounds__(256) void bucket_scatter(const int* __restrict__ src,
                                                      const int* __restrict__ dst, int E,
                                                      int nb, int* __restrict__ gcursor,
                                                      unsigned* __restrict__ bpair) {
    __shared__ int lhist[NBMAX];
    __shared__ int lbase[NBMAX];
    int t = threadIdx.x;
    for (int i = t; i < nb; i += 256) lhist[i] = 0;
    __syncthreads();
    int e0 = blockIdx.x * 4096, e1 = min(e0 + 4096, E);
    for (int e = e0 + t; e < e1; e += 256) atomicAdd(&lhist[dst[e] >> 8], 1);
    __syncthreads();
    for (int i = t; i < nb; i += 256) {
        int c = lhist[i];
        lbase[i] = c ? atomicAdd(&gcursor[i], c) : 0;
        lhist[i] = 0;
    }
    __syncthreads();
    for (int e = e0 + t; e < e1; e += 256) {
        int d = dst[e];
        int b = d >> 8;
        int r = lbase[b] + atomicAdd(&lhist[b], 1);
        if (r < BCAP)
            bpair[(long)b * BCAP + r] = ((unsigned)src[e] << 8) | (unsigned)(d & 255);
    }
}

// Exclusive scan of nb (<512) bucket counts -> gbase, total at gbase[nb].
__global__ void scan_buckets(const int* __restrict__ gcursor, int B, int* __restrict__ gbase) {
    __shared__ int s[512];
    int t = threadIdx.x;
    s[t] = (t < B) ? gcursor[t] : 0;
    __syncthreads();
    for (int off = 1; off < 512; off <<= 1) {
        int v = (t >= off) ? s[t - off] : 0;
        __syncthreads();
        s[t] += v;
        __syncthreads();
    }
    if (t < B) gbase[t] = (t == 0) ? 0 : s[t - 1];
    if (t == 0) gbase[B] = s[511];
}

// One block per bucket: local histogram + scan in LDS, emit row_ptr/dis and
// adj entries packed as (src << 6) | (dst & 63)  (tile-local dst, TILE=64).
__global__ __launch_bounds__(256) void bucket_build(const unsigned* __restrict__ bpair,
                                                    int nb, int N,
                                                    const int* __restrict__ gcursor,
                                                    const int* __restrict__ gbase,
                                                    int* __restrict__ row_ptr,
                                                    float* __restrict__ dis,
                                                    int* __restrict__ adj) {
    __shared__ int hist[256];
    __shared__ int cur[256];
    __shared__ int wsum[4];
    int b = blockIdx.x, t = threadIdx.x;
    int cnt = gcursor[b];
    if (cnt > BCAP) cnt = BCAP;
    int ebase = gbase[b];
    const unsigned* bp = bpair + (long)b * BCAP;

    hist[t] = 0;
    __syncthreads();
    for (int i = t; i < cnt; i += 256) atomicAdd(&hist[bp[i] & 255u], 1);
    __syncthreads();
    int val = hist[t];
    int lane = t & 63, wv = t >> 6;
    int v = val;
#pragma unroll
    for (int off = 1; off < 64; off <<= 1) {
        int u = __shfl_up(v, off, 64);
        if (lane >= off) v += u;
    }
    if (lane == 63) wsum[wv] = v;
    __syncthreads();
    int wo = 0;
#pragma unroll
    for (int w = 0; w < 4; w++)
        if (w < wv) wo += wsum[w];
    int excl = wo + v - val;
    int node = (b << 8) + t;
    if (node < N) {
        row_ptr[node] = ebase + excl;
        dis[node] = rsqrtf((float)(val + 1));  // +1 self-loop
    }
    cur[t] = ebase + excl;
    __syncthreads();
    for (int i = t; i < cnt; i += 256) {
        unsigned p = bp[i];
        unsigned dl = p & 255u;
        int pos = atomicAdd(&cur[dl], 1);
        adj[pos] = (int)((p >> 8) << 6) | (int)(dl & 63u);
    }
    if (b == 0 && t == 0) row_ptr[N] = gbase[nb];
}

// Tile GCN layer on pre-scaled storage s[n] = dis[n]*h[n]:
//   y[n] = dis[n] * ( sum_a s[a] + s[n] );  o = relu(y @ W + b); store (*dis if scale_out)
// Block = 64-node tile. Phase 1: each wave takes a contiguous quarter of the
// tile's CSR edge range, bulk-copies its adjacency slice into wave-private LDS,
// then sweeps 8 group-streams (lane = (group, chunk)) issuing row-gathers in
// batches of 8 (independent addresses from LDS -> 8 loads in flight; no global
// dependent chain). Run-accumulate per lane, flush to LDS fp32 acc via ds atomics
// on node change. Phase 2: per-wave MFMA (16 nodes x 64) @ W (bf16 frags).
__global__ __launch_bounds__(256) void tile_layer(const __half* __restrict__ in,
                                                  const int* __restrict__ row_ptr,
                                                  const int* __restrict__ adj,
                                                  const float* __restrict__ dis,
                                                  const float* __restrict__ Wg,
                                                  const float* __restrict__ bias,
                                                  __half* __restrict__ out,
                                                  int N, int scale_out) {
    __shared__ float acc[TILE * AST];       // 17408 B
    __shared__ int adjbuf[4][ACAP];         // 7168 B, wave-private slices

    int t = threadIdx.x;
    int lane = t & 63;
    int w = t >> 6;
    int gs = lane >> 3, cs = lane & 7;
    int col = lane & 15, quad = lane >> 4;

    int t0 = blockIdx.x * TILE;
    int nend = min(t0 + TILE, N);

    // init: acc row n = s[n] (self-loop term), zeros for padding rows
#pragma unroll
    for (int i = 0; i < 16; i++) {
        int nl = w * 16 + i;
        int n = t0 + nl;
        float v = (n < nend) ? __half2float(in[(long)n * D + lane]) : 0.f;
        acc[nl * AST + lane] = v;
    }
    __syncthreads();

    // ---- edge sweep ----
    int eb = row_ptr[t0];
    int ee = row_ptr[nend];
    int etot = ee - eb;
    int per = (etot + 3) >> 2;
    int a0 = eb + w * per;
    int b0 = min(a0 + per, ee);
    const int4* in4 = (const int4*)in;
    int* adjw = adjbuf[w];

    int cur_nl = -1;
    float racc[8];
#pragma unroll
    for (int q = 0; q < 8; q++) racc[q] = 0.f;

    for (int base = a0; base < b0; base += ACAP) {
        int clen = min(ACAP, b0 - base);
        // cooperative wave-copy of adj slice (coalesced dwords); wave-private,
        // compiler inserts the ds-write->ds-read wait.
        for (int i = lane; i < clen; i += 64) adjw[i] = adj[base + i];

        int glen = (clen + 7) >> 3;
        int gst = gs * glen;
        int gend = min(gst + glen, clen);

        for (int i = gst; i < gend; i += 8) {
            int pk[8];
            bool ok[8];
            int g1 = gend - 1;
#pragma unroll
            for (int q = 0; q < 8; q++) {
                int ii = i + q;
                ok[q] = ii < gend;
                pk[q] = adjw[ok[q] ? ii : g1];
            }
            // 8 independent row-gathers issued together
            int4 rr[8];
#pragma unroll
            for (int q = 0; q < 8; q++) rr[q] = in4[(long)(pk[q] >> 6) * 8 + cs];

#pragma unroll
            for (int q = 0; q < 8; q++) {
                if (ok[q]) {
                    int nl = pk[q] & 63;
                    if (nl != cur_nl) {
                        if (cur_nl >= 0) {
                            float* bp = &acc[cur_nl * AST + cs * 8];
#pragma unroll
                            for (int z = 0; z < 8; z++) atomicAdd(bp + z, racc[z]);
                        }
#pragma unroll
                        for (int z = 0; z < 8; z++) racc[z] = 0.f;
                        cur_nl = nl;
                    }
                    float2 f0 = __half22float2(*(__half2*)&rr[q].x);
                    float2 f1 = __half22float2(*(__half2*)&rr[q].y);
                    float2 f2 = __half22float2(*(__half2*)&rr[q].z);
                    float2 f3 = __half22float2(*(__half2*)&rr[q].w);
                    racc[0] += f0.x; racc[1] += f0.y;
                    racc[2] += f1.x; racc[3] += f1.y;
                    racc[4] += f2.x; racc[5] += f2.y;
                    racc[6] += f3.x; racc[7] += f3.y;
                }
            }
        }
    }
    if (cur_nl >= 0) {
        float* bp = &acc[cur_nl * AST + cs * 8];
#pragma unroll
        for (int q = 0; q < 8; q++) atomicAdd(bp + q, racc[q]);
    }
    __syncthreads();

    // ---- MFMA epilogue: per wave, rows w*16 .. w*16+15 ----
    // B frags (W bf16): B[k=32s+quad*8+j][d=16c+col]  (R7-verified mapping)
    short8 Bf[2][4];
#pragma unroll
    for (int s = 0; s < 2; s++)
#pragma unroll
        for (int c = 0; c < 4; c++) {
            short8 f;
#pragma unroll
            for (int j = 0; j < 8; j++)
                f[j] = (short)f2bf(Wg[(32 * s + quad * 8 + j) * D + 16 * c + col]);
            Bf[s][c] = f;
        }
    float bias_c[4];
#pragma unroll
    for (int c = 0; c < 4; c++) bias_c[c] = bias[16 * c + col];

    // A frags: row m = col, k = 32s + quad*8 + j; scale row by dis (y = dn*acc)
    int arow = w * 16 + col;
    int anode = t0 + arow;
    float dA = (anode < N) ? dis[anode] : 0.f;
    short8 Af[2];
#pragma unroll
    for (int s = 0; s < 2; s++) {
        const float* ap = &acc[arow * AST + 32 * s + quad * 8];
        float4v p0 = *(const float4v*)ap;
        float4v p1 = *(const float4v*)(ap + 4);
        short8 f;
#pragma unroll
        for (int j = 0; j < 4; j++) {
            f[j] = (short)f2bf(p0[j] * dA);
            f[4 + j] = (short)f2bf(p1[j] * dA);
        }
        Af[s] = f;
    }

    float4v accv[4];
#pragma unroll
    for (int c = 0; c < 4; c++) {
        float4v z = {0.f, 0.f, 0.f, 0.f};
        accv[c] = __builtin_amdgcn_mfma_f32_16x16x32_bf16(Af[0], Bf[0][c], z, 0, 0, 0);
        accv[c] = __builtin_amdgcn_mfma_f32_16x16x32_bf16(Af[1], Bf[1][c], accv[c], 0, 0, 0);
    }

    // C layout: col = lane&15 (dim 16c+col), row = quad*4 + r (node)
#pragma unroll
    for (int r = 0; r < 4; r++) {
        int node = t0 + w * 16 + quad * 4 + r;
        if (node < N) {
            float dn = scale_out ? dis[node] : 1.f;
#pragma unroll
            for (int c = 0; c < 4; c++) {
                float vv = fmaxf(accv[c][r] + bias_c[c], 0.f) * dn;
                out[(long)node * D + 16 * c + col] = __float2half(vv);
            }
        }
    }
}

// Pool phase 1: grid-chunked over sorted nodes; per-wave run accumulation,
// one atomicAdd per (graph-run, lane) per wave.
__global__ __launch_bounds__(256) void pool_partial(const __half* __restrict__ h,
                                                    const int* __restrict__ batch, int N,
                                                    int chunk, float* __restrict__ pooled) {
    int lane = threadIdx.x & 63;
    int wv = threadIdx.x >> 6;
    int c0 = blockIdx.x * chunk;
    int c1 = min(c0 + chunk, N);
    int g_cur = -1;
    float acc = 0.f;
    for (int n = c0 + wv; n < c1; n += 4) {
        int g = batch[n];
        if (g != g_cur) {
            if (g_cur >= 0) atomicAdd(&pooled[g_cur * D + lane], acc);
            g_cur = g;
            acc = 0.f;
        }
        acc += __half2float(h[n * D + lane]);
    }
    if (g_cur >= 0) atomicAdd(&pooled[g_cur * D + lane], acc);
}

// Pool phase 2: one wave per graph, dot with lin_w.
__global__ void pool_linear(const float* __restrict__ pooled,
                            const float* __restrict__ lin_w,
                            const float* __restrict__ lin_b,
                            float* __restrict__ out, int G) {
    int lane = threadIdx.x & 63;
    int g = blockIdx.x * (blockDim.x >> 6) + (threadIdx.x >> 6);
    if (g >= G) return;
    float t = pooled[g * D + lane] * lin_w[lane];
#pragma unroll
    for (int off = 32; off >= 1; off >>= 1) t += __shfl_down(t, off, 64);
    if (lane == 0) out[g] = t + lin_b[0];
}

extern "C" void kernel_launch(void* const* d_in, const int* in_sizes, int n_in,
                              void* d_out, int out_size, void* d_ws, size_t ws_size,
                              hipStream_t stream) {
    const float* x      = (const float*)d_in[0];
    const int*   edges  = (const int*)d_in[1];
    const int*   batch  = (const int*)d_in[2];
    const float* W1     = (const float*)d_in[3];
    const float* b1     = (const float*)d_in[4];
    const float* W2     = (const float*)d_in[5];
    const float* b2     = (const float*)d_in[6];
    const float* W3     = (const float*)d_in[7];
    const float* b3     = (const float*)d_in[8];
    const float* lin_w  = (const float*)d_in[9];
    const float* lin_b  = (const float*)d_in[10];
    float* out = (float*)d_out;

    const int N = in_sizes[2];        // 100000
    const int E = in_sizes[1] / 2;    // 1600000
    const int G = out_size;           // 64 graphs
    const int nb = (N + 255) >> 8;    // 391 buckets of 256 nodes

    const int* e_src = edges;         // edge_index[0]
    const int* e_dst = edges + E;     // edge_index[1]

    // workspace layout (4B-element offsets, 64-elem aligned)
    auto al = [](long v) { return (v + 63) & ~63L; };
    long o_gcur   = 0;                       // NBMAX ints
    long o_pooled = al(o_gcur + NBMAX);      // G*D floats
    long o_gbase  = al(o_pooled + (long)G * D);
    long o_rowptr = al(o_gbase + nb + 1);
    long o_dis    = al(o_rowptr + N + 1);
    long o_adjs   = al(o_dis + N);
    long o_xh     = al(o_adjs + E);              // N*D halves
    long o_hA     = al(o_xh + (long)N * D / 2);  // aliases bpair (8MB < 25.6MB slot)
    long o_hB     = o_hA + (long)N * D;          // fp32-sized slots used as half buffers

    int*    gcursor = (int*)d_ws + o_gcur;
    float*  pooled  = (float*)d_ws + o_pooled;
    int*    gbase   = (int*)d_ws + o_gbase;
    int*    row_ptr = (int*)d_ws + o_rowptr;
    float*  dis     = (float*)d_ws + o_dis;
    int*    adj     = (int*)d_ws + o_adjs;
    __half* xh      = (__half*)((float*)d_ws + o_xh);
    __half* hA      = (__half*)((float*)d_ws + o_hA);
    __half* hB      = (__half*)((float*)d_ws + o_hB);
    // bpair (nb*BCAP uints = 8 MB) aliases hA slot: dead before layer 2 writes hA.
    unsigned* bpair = (unsigned*)hA;

    // zero gcursor + pooled (contiguous)
    int nz = (int)(o_pooled + (long)G * D);
    zero_ints<<<(nz + 255) / 256, 256, 0, stream>>>((int*)d_ws, nz);

    // CSR build first (produces dis), then pre-scaled fp16 convert of x
    bucket_scatter<<<(E + 4095) / 4096, 256, 0, stream>>>(e_src, e_dst, E, nb, gcursor, bpair);
    scan_buckets<<<1, 512, 0, stream>>>(gcursor, nb, gbase);
    bucket_build<<<nb, 256, 0, stream>>>(bpair, nb, N, gcursor, gbase, row_ptr, dis, adj);

    int n2 = N * D / 2;
    prescale_x<<<(n2 + 255) / 256, 256, 0, stream>>>(x, dis, xh, n2);

    // fused GCN layers: xh -> hB -> hA -> hB
    // layers 1,2 store dis-pre-scaled output; layer 3 stores plain relu for pooling
    const int tl_blocks = (N + TILE - 1) / TILE;
    tile_layer<<<tl_blocks, 256, 0, stream>>>(xh, row_ptr, adj, dis, W1, b1, hB, N, 1);
    tile_layer<<<tl_blocks, 256, 0, stream>>>(hB, row_ptr, adj, dis, W2, b2, hA, N, 1);
    tile_layer<<<tl_blocks, 256, 0, stream>>>(hA, row_ptr, adj, dis, W3, b3, hB, N, 0);

    // pool + final linear
    const int pool_blocks = 512;
    const int chunk = (N + pool_blocks - 1) / pool_blocks;
    pool_partial<<<pool_blocks, 256, 0, stream>>>(hB, batch, N, chunk, pooled);
    pool_linear<<<(G + 3) / 4, 256, 0, stream>>>(pooled, lin_w, lin_b, out, G);
}